// Round 4
// baseline (137.963 us; speedup 1.0000x reference)
//
#include <hip/hip_runtime.h>

// Problem constants
#define N_   8
#define C_   32
#define H_   256
#define W_   256
#define HW_  (H_ * W_)

// ---------------------------------------------------------------------------
// Kernel 1: per-(n,c) instance-norm stats folded with gamma/beta into
//           scale/shift:  xn = x*scale + shift
// grid = 256 (one wg per (n,c) plane), block = 1024 (16 waves)
// Measured-safe: dense float4 stream, ~BW floor (~20 us).
// ---------------------------------------------------------------------------
__global__ __launch_bounds__(1024) void stats_kernel(
    const float* __restrict__ x, const float* __restrict__ gamma,
    const float* __restrict__ beta, float2* __restrict__ ss)
{
    const int nc = blockIdx.x;      // n*32 + c
    const int t  = threadIdx.x;
    const float4* p = (const float4*)(x + (size_t)nc * HW_);

    float s0 = 0.f, s1 = 0.f, s2 = 0.f, s3 = 0.f;
    float q0 = 0.f, q1 = 0.f, q2 = 0.f, q3 = 0.f;
    #pragma unroll
    for (int i = 0; i < 16; ++i) {
        float4 v = p[t + (i << 10)];
        s0 += v.x; s1 += v.y; s2 += v.z; s3 += v.w;
        q0 = fmaf(v.x, v.x, q0); q1 = fmaf(v.y, v.y, q1);
        q2 = fmaf(v.z, v.z, q2); q3 = fmaf(v.w, v.w, q3);
    }
    double s = (double)s0 + (double)s1 + (double)s2 + (double)s3;
    double q = (double)q0 + (double)q1 + (double)q2 + (double)q3;
    #pragma unroll
    for (int off = 32; off > 0; off >>= 1) {
        s += __shfl_down(s, off);
        q += __shfl_down(q, off);
    }
    __shared__ double rs[16], rq[16];
    const int wid = t >> 6;
    if ((t & 63) == 0) { rs[wid] = s; rq[wid] = q; }
    __syncthreads();
    if (t == 0) {
        double S = 0.0, Q = 0.0;
        #pragma unroll
        for (int i = 0; i < 16; ++i) { S += rs[i]; Q += rq[i]; }
        double mean = S / (double)HW_;
        double var  = Q / (double)HW_ - mean * mean;
        double grs  = (double)gamma[nc & (C_ - 1)] / sqrt(var + 1e-5);
        float scale = (float)grs;
        float shift = (float)((double)beta[nc & (C_ - 1)] - mean * grs);
        ss[nc] = make_float2(scale, shift);
    }
}

// ---------------------------------------------------------------------------
// Kernel 2: fused  normalize -> pooled sparse field -> 1x1 conv -> relu
//
// For each 2x2 spatial pooling block (h-blocks align to even h; w-blocks
// cover {2j-1,2j}), m = max of 4 normalized values (pads = 0), s* = first
// argmax in (row,kw) order; contribution 0.75*m (m>0) or 0.25*m (m<=0,
// zeroed if s* is a pad) at s*.  out = relu(b + W * collapsed).
//
// grid = (128 h-pairs, 4 w-quarters, 8 n), block = 256 (4 waves)
// LDS ~10 KB -> 8 wg/CU (thread-limited).  sWT padded to stride 36 so the
// transpose-staging writes are bank-spread (round-2/3's 1.31M conflicts).
// ---------------------------------------------------------------------------
__global__ __launch_bounds__(256, 8) void fused_kernel(
    const float* __restrict__ x, const float2* __restrict__ ss,
    const float* __restrict__ Wm, const float* __restrict__ bias,
    float* __restrict__ out)
{
    const int k   = blockIdx.x;   // h-pair: rows 2k, 2k+1
    const int qtr = blockIdx.y;   // w window [64*qtr, 64*qtr+64)
    const int n   = blockIdx.z;
    const int t   = threadIdx.x;
    const int w0  = qtr << 6;

    __shared__ float         sWT[C_][36];  // sWT[c][o] = W[o,c]; stride 36: pad
    __shared__ float         sV[C_][34];   // block values, local jl = 0..32
    __shared__ unsigned char sP[C_][36];   // argmax pos code 0..3

    // stage W^T (Wm is [o][c] row-major); coalesced global, 4-way LDS banks
    #pragma unroll
    for (int r = 0; r < 4; ++r) {
        int i = t + (r << 8);
        sWT[i & 31][i >> 5] = Wm[i];
    }

    // ---- Phase A: vectorized loads + per-block max/argmax ------------------
    // thread owns 8 contiguous local cols [8*li, 8*li+8), both rows
    const int c  = t >> 3;        // 0..31
    const int li = t & 7;         // 0..7
    const float2 sc = ss[n * C_ + c];
    const float* plane = x + (size_t)(n * C_ + c) * HW_ + (size_t)(2 * k) * W_;
    const float* rowb  = plane + w0 + 8 * li;
    float4 u00 = ((const float4*)rowb)[0];
    float4 u01 = ((const float4*)rowb)[1];
    float4 u10 = ((const float4*)(rowb + W_))[0];
    float4 u11 = ((const float4*)(rowb + W_))[1];

    // boundary column shared with neighbor quarter:
    //   li==0 & qtr>0 -> w0-1 ;  li==7 & qtr<3 -> w0+64
    float bm = 0.f; int br = 0;
    {
        bool needL = (li == 0) && (qtr > 0);
        bool needR = (li == 7) && (qtr < 3);
        if (needL || needR) {
            const float* bp = plane + (needL ? (w0 - 1) : (w0 + 64));
            float p0 = fmaf(bp[0],  sc.x, sc.y);
            float p1 = fmaf(bp[W_], sc.x, sc.y);
            bm = fmaxf(p0, p1); br = (p1 > p0) ? 1 : 0;
        }
    }

    float vm[8];
    unsigned vr = 0;
    {
        float a0, a1;
        a0 = fmaf(u00.x, sc.x, sc.y); a1 = fmaf(u10.x, sc.x, sc.y);
        vm[0] = fmaxf(a0, a1); if (a1 > a0) vr |= 1u << 0;
        a0 = fmaf(u00.y, sc.x, sc.y); a1 = fmaf(u10.y, sc.x, sc.y);
        vm[1] = fmaxf(a0, a1); if (a1 > a0) vr |= 1u << 1;
        a0 = fmaf(u00.z, sc.x, sc.y); a1 = fmaf(u10.z, sc.x, sc.y);
        vm[2] = fmaxf(a0, a1); if (a1 > a0) vr |= 1u << 2;
        a0 = fmaf(u00.w, sc.x, sc.y); a1 = fmaf(u10.w, sc.x, sc.y);
        vm[3] = fmaxf(a0, a1); if (a1 > a0) vr |= 1u << 3;
        a0 = fmaf(u01.x, sc.x, sc.y); a1 = fmaf(u11.x, sc.x, sc.y);
        vm[4] = fmaxf(a0, a1); if (a1 > a0) vr |= 1u << 4;
        a0 = fmaf(u01.y, sc.x, sc.y); a1 = fmaf(u11.y, sc.x, sc.y);
        vm[5] = fmaxf(a0, a1); if (a1 > a0) vr |= 1u << 5;
        a0 = fmaf(u01.z, sc.x, sc.y); a1 = fmaf(u11.z, sc.x, sc.y);
        vm[6] = fmaxf(a0, a1); if (a1 > a0) vr |= 1u << 6;
        a0 = fmaf(u01.w, sc.x, sc.y); a1 = fmaf(u11.w, sc.x, sc.y);
        vm[7] = fmaxf(a0, a1); if (a1 > a0) vr |= 1u << 7;
    }

    // left straddle (local col 8*li - 1) from previous lane (same c for li>0)
    const float pvm = __shfl_up(vm[7], 1);
    const int   pvr = __shfl_up((int)((vr >> 7) & 1u), 1);

    // blocks bl = 4*li + b : left col = local 2*bl-1, right col = local 2*bl
    #pragma unroll
    for (int b = 0; b < 4; ++b) {
        float vL; int rL; bool padL = false;
        if (b == 0) {
            if (li == 0) {
                if (qtr == 0) { vL = 0.f; rL = 0; padL = true; }  // left spatial pad
                else          { vL = bm;  rL = br; }              // w0-1, real
            } else { vL = pvm; rL = pvr; }
        } else {
            vL = vm[2 * b - 1]; rL = (int)((vr >> (2 * b - 1)) & 1u);
        }
        float vR = vm[2 * b]; int rR = (int)((vr >> (2 * b)) & 1u);
        bool chooseL = (vL > vR) || ((vL == vR) && (rL <= rR));
        float m   = chooseL ? vL : vR;
        int   p   = chooseL ? (rL << 1) : ((rR << 1) | 1);
        float val = m * (m > 0.f ? 0.75f : 0.25f);
        if (chooseL && padL) val = 0.f;
        int jl = 4 * li + b;
        sV[c][jl] = val;
        sP[c][jl] = (unsigned char)p;
    }
    if (li == 7) {   // block jl = 32: left = local col 63, right = boundary
        float vL = vm[7]; int rL = (int)((vr >> 7) & 1u);
        float vR; int rR; bool padR;
        if (qtr < 3) { vR = bm;  rR = br; padR = false; }  // w0+64, real
        else         { vR = 0.f; rR = 0;  padR = true;  }  // right spatial pad
        bool chooseL = (vL > vR) || ((vL == vR) && (rL <= rR));
        float m   = chooseL ? vL : vR;
        int   p   = chooseL ? (rL << 1) : ((rR << 1) | 1);
        float val = m * (m > 0.f ? 0.75f : 0.25f);
        if (!chooseL && padR) val = 0.f;
        sV[c][32] = val;
        sP[c][32] = (unsigned char)p;
    }
    __syncthreads();

    // ---- Phase B: lane owns ONE output column (both rows), 8 out-channels --
    const int wv = t >> 6;        // wave 0..3
    const int ob = wv << 3;       // o-octet base
    const int L  = t & 63;        // local out col 0..63
    const int jl = (L + 1) >> 1;  // feeding block
    const int pm0 = (L & 1) ? 0 : 1;  // row-0 match code

    float acc0[8], acc1[8];
    #pragma unroll
    for (int oo = 0; oo < 8; ++oo) {
        float bo = bias[ob + oo];
        acc0[oo] = bo; acc1[oo] = bo;
    }

    #pragma unroll 8
    for (int cc = 0; cc < C_; ++cc) {
        float v = sV[cc][jl];
        int   p = sP[cc][jl];
        float m0 = (p == pm0)     ? v : 0.f;
        float m1 = (p == pm0 + 2) ? v : 0.f;
        float4 wa = *(const float4*)&sWT[cc][ob];
        float4 wb = *(const float4*)&sWT[cc][ob + 4];
        acc0[0] = fmaf(m0, wa.x, acc0[0]);
        acc0[1] = fmaf(m0, wa.y, acc0[1]);
        acc0[2] = fmaf(m0, wa.z, acc0[2]);
        acc0[3] = fmaf(m0, wa.w, acc0[3]);
        acc0[4] = fmaf(m0, wb.x, acc0[4]);
        acc0[5] = fmaf(m0, wb.y, acc0[5]);
        acc0[6] = fmaf(m0, wb.z, acc0[6]);
        acc0[7] = fmaf(m0, wb.w, acc0[7]);
        acc1[0] = fmaf(m1, wa.x, acc1[0]);
        acc1[1] = fmaf(m1, wa.y, acc1[1]);
        acc1[2] = fmaf(m1, wa.z, acc1[2]);
        acc1[3] = fmaf(m1, wa.w, acc1[3]);
        acc1[4] = fmaf(m1, wb.x, acc1[4]);
        acc1[5] = fmaf(m1, wb.y, acc1[5]);
        acc1[6] = fmaf(m1, wb.z, acc1[6]);
        acc1[7] = fmaf(m1, wb.w, acc1[7]);
    }

    // ---- store: relu, lanes consecutive in w -> coalesced ------------------
    float* obase = out + (size_t)(n * C_ + ob) * HW_
                       + (size_t)(2 * k) * W_ + w0 + L;
    #pragma unroll
    for (int oo = 0; oo < 8; ++oo) {
        obase[(size_t)oo * HW_]      = fmaxf(acc0[oo], 0.f);
        obase[(size_t)oo * HW_ + W_] = fmaxf(acc1[oo], 0.f);
    }
}

extern "C" void kernel_launch(void* const* d_in, const int* in_sizes, int n_in,
                              void* d_out, int out_size, void* d_ws, size_t ws_size,
                              hipStream_t stream) {
    const float* x     = (const float*)d_in[0];
    const float* gamma = (const float*)d_in[1];
    const float* beta  = (const float*)d_in[2];
    const float* Wm    = (const float*)d_in[3];
    const float* bias  = (const float*)d_in[4];
    float* out  = (float*)d_out;
    float2* ss  = (float2*)d_ws;    // 256 x {scale, shift}

    stats_kernel<<<N_ * C_, 1024, 0, stream>>>(x, gamma, beta, ss);
    fused_kernel<<<dim3(H_ / 2, 4, N_), 256, 0, stream>>>(x, ss, Wm, bias, out);
}